// Round 2
// baseline (367.364 us; speedup 1.0000x reference)
//
#include <hip/hip_runtime.h>

#define N_NODES 100000
#define N_EDGES 800000
#define NEG 0.2f
#define PB_SHIFT 8
#define PB_NODES 256
#define N_PBKT ((N_NODES + PB_NODES - 1) / PB_NODES)   // 391
#define TILE_E 4096
#define EPT 16          // edges per thread in partition (TILE_E / 256)
#define PREP_BLOCKS ((N_NODES * 128 / 4 + 255) / 256)  // 12500
#define HIST_BLOCKS 192

typedef __attribute__((ext_vector_type(8))) short bf16x8;
typedef __attribute__((ext_vector_type(4))) float f32x4;
typedef _Float16 f16;
typedef __attribute__((ext_vector_type(8))) _Float16 f16x8;

__device__ inline unsigned short f2bf(float f) {   // RNE f32 -> bf16
    unsigned u = __float_as_uint(f);
    u += 0x7fffu + ((u >> 16) & 1u);
    return (unsigned short)(u >> 16);
}
__device__ inline float bf2f_lo(unsigned u) { return __uint_as_float(u << 16); }
__device__ inline float bf2f_hi(unsigned u) { return __uint_as_float(u & 0xffff0000u); }
__device__ inline float lexp(float l) { return __expf(l > 0.f ? l : NEG * l); }

// ---------------------------------------------------------------------------
// prep_w: pack W (and Aalpha = W·a, ct==8) into MFMA B-fragment order.
// Also zeroes the bucket-count array and the adj/coef end-pads.
// ---------------------------------------------------------------------------
__global__ __launch_bounds__(256) void prep_w_kernel(
    const float* __restrict__ W_in, const float* __restrict__ W_out,
    const float* __restrict__ as_in, const float* __restrict__ ad_in,
    const float* __restrict__ as_out, const float* __restrict__ ad_out,
    unsigned short* __restrict__ Wf, int* __restrict__ bcnt,
    int* __restrict__ adj_in, int* __restrict__ adj_out,
    f16* __restrict__ w_in, f16* __restrict__ w_out)
{
    const int t = blockIdx.x * 256 + threadIdx.x;
    if (t < 2 * N_PBKT) bcnt[t] = 0;
    if (t < 8) { adj_in[N_EDGES + t] = 0; adj_out[N_EDGES + t] = 0; }
    if (t < 64) {
        ((unsigned short*)w_in)[(long long)N_EDGES * 8 + t] = 0;
        ((unsigned short*)w_out)[(long long)N_EDGES * 8 + t] = 0;
    }
    if (t >= 2 * 4 * 9 * 64) return;
    const int lane = t & 63;
    const int rest = t >> 6;
    const int ct  = rest % 9;
    const int kb  = (rest / 9) & 3;
    const int dir = rest / 36;
    const float* W  = dir ? W_out  : W_in;
    const float* as = dir ? as_out : as_in;
    const float* ad = dir ? ad_out : ad_in;
    const int m16 = lane & 15, quad = lane >> 4;

    bf16x8 o;
#pragma unroll
    for (int j = 0; j < 8; ++j) {
        const int k = kb * 32 + quad * 8 + j;
        float v;
        if (ct < 8) {
            v = W[k * 128 + ct * 16 + m16];
        } else {
            const float* av = (m16 < 8) ? as : ad;
            const int hh = m16 & 7;
            v = 0.f;
            for (int c = 0; c < 16; ++c)
                v += W[k * 128 + hh * 16 + c] * av[hh * 16 + c];
        }
        o[j] = (short)f2bf(v);
    }
    *(bf16x8*)&Wf[(long long)t * 8] = o;
}

// ---------------------------------------------------------------------------
// fused prep_x + coarse bucket histogram.
// ---------------------------------------------------------------------------
__global__ __launch_bounds__(256) void prep_hist_kernel(
    const float* __restrict__ x, unsigned short* __restrict__ x_bf,
    const int* __restrict__ ei, int* __restrict__ bcnt)
{
    const int tid = threadIdx.x;
    if (blockIdx.x < PREP_BLOCKS) {
        const int i = (blockIdx.x * 256 + tid) * 4;
        if (i >= N_NODES * 128) return;
        const float4 v = *(const float4*)&x[i];
        ushort4 o;
        o.x = f2bf(v.x); o.y = f2bf(v.y); o.z = f2bf(v.z); o.w = f2bf(v.w);
        *(ushort4*)&x_bf[i] = o;
        return;
    }
    // histogram part
    __shared__ int bh[2 * N_PBKT];
    for (int i = tid; i < 2 * N_PBKT; i += 256) bh[i] = 0;
    __syncthreads();
    const int hb = blockIdx.x - PREP_BLOCKS;
    for (int e = hb * 256 + tid; e < N_EDGES; e += HIST_BLOCKS * 256) {
        const int s = ei[e];
        const int t = ei[N_EDGES + e];
        atomicAdd(&bh[t >> PB_SHIFT], 1);               // dir0: group by dst
        atomicAdd(&bh[N_PBKT + (s >> PB_SHIFT)], 1);    // dir1: group by src
    }
    __syncthreads();
    for (int i = tid; i < 2 * N_PBKT; i += 256) {
        const int v = bh[i];
        if (v) atomicAdd(&bcnt[i], v);
    }
}

// ---------------------------------------------------------------------------
// gemm: h = bf16(x) @ bf16(W) via MFMA; alpha logits from the 9th column tile.
// ---------------------------------------------------------------------------
__global__ __launch_bounds__(256) void gemm_kernel(
    const unsigned short* __restrict__ x_bf,
    const unsigned short* __restrict__ Wf,
    unsigned short* __restrict__ h_in, unsigned short* __restrict__ h_out,
    float* __restrict__ asrc_in, float* __restrict__ adst_in,
    float* __restrict__ asrc_out, float* __restrict__ adst_out)
{
    const int dir = blockIdx.y;
    unsigned short* h = dir ? h_out : h_in;
    float* asrc = dir ? asrc_out : asrc_in;
    float* adst = dir ? adst_out : adst_in;

    const int tid  = threadIdx.x;
    const int lane = tid & 63;
    const int wave = tid >> 6;
    const int m16  = lane & 15;
    const int quad = lane >> 4;
    const int rbase = blockIdx.x * 128 + wave * 32;

    f32x4 acc[2][8];
    f32x4 acc_a[2];
#pragma unroll
    for (int rt = 0; rt < 2; ++rt) {
        acc_a[rt] = f32x4{0.f, 0.f, 0.f, 0.f};
#pragma unroll
        for (int ct = 0; ct < 8; ++ct)
            acc[rt][ct] = f32x4{0.f, 0.f, 0.f, 0.f};
    }

    const unsigned short* wf = Wf + (long long)dir * 4 * 9 * 64 * 8;

#pragma unroll
    for (int kb = 0; kb < 4; ++kb) {
        const int k0 = kb * 32 + quad * 8;
        bf16x8 a[2];
#pragma unroll
        for (int rt = 0; rt < 2; ++rt) {
            int r = rbase + rt * 16 + m16;
            r = r < N_NODES ? r : N_NODES - 1;   // clamp: stores are guarded
            a[rt] = *(const bf16x8*)&x_bf[(long long)r * 128 + k0];
        }
#pragma unroll
        for (int ct = 0; ct < 9; ++ct) {
            const bf16x8 b = *(const bf16x8*)&wf[(long long)((kb * 9 + ct) * 64 + lane) * 8];
            if (ct < 8) {
                acc[0][ct] = __builtin_amdgcn_mfma_f32_16x16x32_bf16(a[0], b, acc[0][ct], 0, 0, 0);
                acc[1][ct] = __builtin_amdgcn_mfma_f32_16x16x32_bf16(a[1], b, acc[1][ct], 0, 0, 0);
            } else {
                acc_a[0] = __builtin_amdgcn_mfma_f32_16x16x32_bf16(a[0], b, acc_a[0], 0, 0, 0);
                acc_a[1] = __builtin_amdgcn_mfma_f32_16x16x32_bf16(a[1], b, acc_a[1], 0, 0, 0);
            }
        }
    }

#pragma unroll
    for (int rt = 0; rt < 2; ++rt) {
#pragma unroll
        for (int r = 0; r < 4; ++r) {
            const int row = rbase + rt * 16 + quad * 4 + r;
            if (row < N_NODES) {
                unsigned short* hp = &h[(long long)row * 128 + m16];
#pragma unroll
                for (int ct = 0; ct < 8; ++ct)
                    hp[ct * 16] = f2bf(acc[rt][ct][r]);
                const float av = acc_a[rt][r];
                if (m16 < 8) asrc[row * 8 + m16] = av;
                else         adst[row * 8 + (m16 - 8)] = av;
            }
        }
    }
}

// ---------------------------------------------------------------------------
// CSR build: scan bucket counts -> boffs (persistent) + gcur (consumed)
// ---------------------------------------------------------------------------
__global__ __launch_bounds__(512) void bucket_scan_kernel(
    const int* __restrict__ bcnt,
    int* __restrict__ boffs0, int* __restrict__ boffs1,
    int* __restrict__ gcur,
    int* __restrict__ offs_in, int* __restrict__ offs_out)
{
    const int dir = blockIdx.x;
    const int* c = bcnt + dir * N_PBKT;
    int* bo = dir ? boffs1 : boffs0;
    int* gc = gcur + dir * N_PBKT;

    __shared__ int sm[512];
    const int tid = threadIdx.x;
    const int v = (tid < N_PBKT) ? c[tid] : 0;
    sm[tid] = v;
    __syncthreads();
#pragma unroll
    for (int off = 1; off < 512; off <<= 1) {
        int t = (tid >= off) ? sm[tid - off] : 0;
        __syncthreads();
        sm[tid] += t;
        __syncthreads();
    }
    if (tid < N_PBKT) {
        const int excl = sm[tid] - v;
        bo[tid] = excl;
        gc[tid] = excl;
    }
    if (tid == N_PBKT - 1) bo[N_PBKT] = sm[tid];   // == N_EDGES
    if (tid == 0) (dir ? offs_out : offs_in)[N_NODES] = N_EDGES;
}

// partition: tile of 4096 edges in registers; LDS hist; one global atomic per
// (block,bucket); clustered writes via LDS cursors. Pair packed (val<<8)|keylow.
__global__ __launch_bounds__(256) void partition_kernel(
    const int* __restrict__ ei, int* __restrict__ gcur,
    int* __restrict__ binned0, int* __restrict__ binned1)
{
    const int dir = blockIdx.y;
    int* binned = dir ? binned1 : binned0;
    int* gc = gcur + dir * N_PBKT;

    __shared__ int hist[N_PBKT];
    __shared__ int curs[N_PBKT];
    const int tid = threadIdx.x;
    for (int i = tid; i < N_PBKT; i += 256) hist[i] = 0;
    __syncthreads();

    const int e0 = blockIdx.x * TILE_E;
    int key[EPT], val[EPT];
#pragma unroll
    for (int i = 0; i < EPT; ++i) {
        const int e = e0 + i * 256 + tid;
        if (e < N_EDGES) {
            const int s = ei[e];
            const int t = ei[N_EDGES + e];
            key[i] = dir ? s : t;
            val[i] = dir ? t : s;
            atomicAdd(&hist[key[i] >> PB_SHIFT], 1);
        } else {
            key[i] = -1; val[i] = 0;
        }
    }
    __syncthreads();
    for (int b = tid; b < N_PBKT; b += 256) {
        const int c = hist[b];
        curs[b] = c ? atomicAdd(&gc[b], c) : 0;
    }
    __syncthreads();
#pragma unroll
    for (int i = 0; i < EPT; ++i) {
        if (key[i] >= 0) {
            const int pos = atomicAdd(&curs[key[i] >> PB_SHIFT], 1);
            binned[pos] = (val[i] << 8) | (key[i] & (PB_NODES - 1));
        }
    }
}

// ---------------------------------------------------------------------------
// place v2: one block per bucket. Phases:
//   1. stage adst (bucket's 256 nodes) into LDS transposed [8][256]; zero den.
//   2. fine count + scan + cursors; write offs.
//   3. scatter loop: adj[pos] = packed (src<<8)|loc; simultaneously compute
//      w = exp(leaky(asrc+adst)) and accumulate per-(node,head) denominator
//      in LDS via ds_add_f32 ([8][256] layout: lanes hit distinct banks).
//   4. invert den -> rden in LDS.
//   5. CSR-ordered pass over the just-written adj (L1-hot): recompute w,
//      multiply by rden, store pre-normalized fp16 coefs with fully
//      COALESCED 16B stores (this was the round-1 regression: scattered
//      32B f32 stores inside the cursor loop).
// ---------------------------------------------------------------------------
__global__ __launch_bounds__(256) void place_kernel(
    const int* __restrict__ binned0, const int* __restrict__ binned1,
    const int* __restrict__ boffs0, const int* __restrict__ boffs1,
    int* __restrict__ adj_in, int* __restrict__ adj_out,
    int* __restrict__ offs_in, int* __restrict__ offs_out,
    const float* __restrict__ asrc_in, const float* __restrict__ adst_in,
    const float* __restrict__ asrc_out, const float* __restrict__ adst_out,
    f16* __restrict__ w_in, f16* __restrict__ w_out)
{
    const int b   = blockIdx.x;
    const int dir = blockIdx.y;
    const int* bp = dir ? binned1 : binned0;
    const int* bo = dir ? boffs1  : boffs0;
    int* adj  = dir ? adj_out  : adj_in;
    int* offs = dir ? offs_out : offs_in;
    const float* asrc = dir ? asrc_out : asrc_in;
    const float* adst = dir ? adst_out : adst_in;
    f16* wx = dir ? w_out : w_in;

    const int base = b << PB_SHIFT;
    const int beg = bo[b], end = bo[b + 1];
    const int tid = threadIdx.x;

    __shared__ int cnt[PB_NODES];
    __shared__ int sc[PB_NODES];
    __shared__ int cur[PB_NODES];
    __shared__ float sadst[8 * PB_NODES];   // [head][loc]
    __shared__ float sden[8 * PB_NODES];    // [head][loc]

    // phase 1: stage adst transposed; zero den
    {
        const int node = base + tid;
        float4 d0 = float4{0.f, 0.f, 0.f, 0.f}, d1 = float4{0.f, 0.f, 0.f, 0.f};
        if (node < N_NODES) {
            d0 = *(const float4*)&adst[node * 8];
            d1 = *(const float4*)&adst[node * 8 + 4];
        }
        sadst[0 * 256 + tid] = d0.x; sadst[1 * 256 + tid] = d0.y;
        sadst[2 * 256 + tid] = d0.z; sadst[3 * 256 + tid] = d0.w;
        sadst[4 * 256 + tid] = d1.x; sadst[5 * 256 + tid] = d1.y;
        sadst[6 * 256 + tid] = d1.z; sadst[7 * 256 + tid] = d1.w;
#pragma unroll
        for (int h = 0; h < 8; ++h) sden[h * 256 + tid] = 0.f;
        cnt[tid] = 0;
    }
    __syncthreads();

    // phase 2: count + scan
    for (int p = beg + tid; p < end; p += 256)
        atomicAdd(&cnt[bp[p] & (PB_NODES - 1)], 1);
    __syncthreads();
    const int v = cnt[tid];
    sc[tid] = v;
    __syncthreads();
#pragma unroll
    for (int off = 1; off < PB_NODES; off <<= 1) {
        int t = (tid >= off) ? sc[tid - off] : 0;
        __syncthreads();
        sc[tid] += t;
        __syncthreads();
    }
    const int excl = beg + sc[tid] - v;
    cur[tid] = excl;
    const int node = base + tid;
    if (node < N_NODES) offs[node] = excl;
    __syncthreads();

    // phase 3: scatter + denominator accumulation
    for (int p = beg + tid; p < end; p += 256) {
        const int pk  = bp[p];
        const int loc = pk & (PB_NODES - 1);
        const int src = pk >> 8;
        const int pos = atomicAdd(&cur[loc], 1);
        adj[pos] = pk;
        const float4 s0 = *(const float4*)&asrc[src * 8];
        const float4 s1 = *(const float4*)&asrc[src * 8 + 4];
        float w[8];
        w[0] = lexp(s0.x + sadst[0 * 256 + loc]);
        w[1] = lexp(s0.y + sadst[1 * 256 + loc]);
        w[2] = lexp(s0.z + sadst[2 * 256 + loc]);
        w[3] = lexp(s0.w + sadst[3 * 256 + loc]);
        w[4] = lexp(s1.x + sadst[4 * 256 + loc]);
        w[5] = lexp(s1.y + sadst[5 * 256 + loc]);
        w[6] = lexp(s1.z + sadst[6 * 256 + loc]);
        w[7] = lexp(s1.w + sadst[7 * 256 + loc]);
#pragma unroll
        for (int h = 0; h < 8; ++h)
            atomicAdd(&sden[h * 256 + loc], w[h]);
    }
    __syncthreads();

    // phase 4: invert
#pragma unroll
    for (int h = 0; h < 8; ++h) {
        const float d = sden[h * 256 + tid];
        sden[h * 256 + tid] = d > 0.f ? 1.f / d : 0.f;
    }
    __syncthreads();

    // phase 5: CSR-ordered normalized-coef stream (coalesced 16B stores)
    for (int p = beg + tid; p < end; p += 256) {
        const int pk  = adj[p];
        const int loc = pk & (PB_NODES - 1);
        const int src = pk >> 8;
        const float4 s0 = *(const float4*)&asrc[src * 8];
        const float4 s1 = *(const float4*)&asrc[src * 8 + 4];
        f16x8 o;
        o[0] = (f16)(lexp(s0.x + sadst[0 * 256 + loc]) * sden[0 * 256 + loc]);
        o[1] = (f16)(lexp(s0.y + sadst[1 * 256 + loc]) * sden[1 * 256 + loc]);
        o[2] = (f16)(lexp(s0.z + sadst[2 * 256 + loc]) * sden[2 * 256 + loc]);
        o[3] = (f16)(lexp(s0.w + sadst[3 * 256 + loc]) * sden[3 * 256 + loc]);
        o[4] = (f16)(lexp(s1.x + sadst[4 * 256 + loc]) * sden[4 * 256 + loc]);
        o[5] = (f16)(lexp(s1.y + sadst[5 * 256 + loc]) * sden[5 * 256 + loc]);
        o[6] = (f16)(lexp(s1.z + sadst[6 * 256 + loc]) * sden[6 * 256 + loc]);
        o[7] = (f16)(lexp(s1.w + sadst[7 * 256 + loc]) * sden[7 * 256 + loc]);
        *(f16x8*)&wx[(long long)p * 8] = o;
    }
}

// ---------------------------------------------------------------------------
// Gather v4: one wave per node, wave-uniform n so offs/adj go through the
// scalar pipe (adj packed (src<<8)|loc -> scalar shift). Coefs are
// pre-normalized fp16 in CSR order: one coalesced 128B load per 8 neighbors.
// No exp, no denominator, no division, no reduction — pure weighted gather.
// ---------------------------------------------------------------------------
__global__ __launch_bounds__(256) void gather_kernel(
    const int* __restrict__ offs_in, const int* __restrict__ adj_in,
    const int* __restrict__ offs_out, const int* __restrict__ adj_out,
    const unsigned short* __restrict__ h_in, const unsigned short* __restrict__ h_out,
    const f16* __restrict__ w_in, const f16* __restrict__ w_out,
    const float* __restrict__ b_in, const float* __restrict__ b_out,
    float* __restrict__ out)
{
    int n = (blockIdx.x * 256 + threadIdx.x) >> 6;
    if (n >= N_NODES) return;
    n = __builtin_amdgcn_readfirstlane(n);
    const int lane = threadIdx.x & 63;
    const int c0 = lane * 2;
    const int hh = lane >> 3;        // head this lane accumulates for
    const int g8 = lane & 7;         // neighbor slot this lane owns
    const int grpbase = lane & 56;   // hh*8: base lane of this head group

    float acc0 = b_in[c0] + b_out[c0];
    float acc1 = b_in[c0 + 1] + b_out[c0 + 1];

#define DIR_BLOCK(OFFS, ADJ, HX, WX)                                           \
    {                                                                          \
        const int beg = OFFS[n], end = OFFS[n + 1];                            \
        if (end > beg) {                                                       \
            float num0 = 0.f, num1 = 0.f;                                      \
            for (int p = beg; p < end; p += 8) {                               \
                const int q = p + g8;                                          \
                const float wl = (q < end)                                     \
                    ? (float)WX[(long long)q * 8 + hh] : 0.f;                  \
                _Pragma("unroll")                                              \
                for (int g = 0; g < 8; ++g) {                                  \
                    const int nb = ADJ[p + g] >> 8;          /* scalar */      \
                    const float w_g = __shfl(wl, grpbase + g, 64);             \
                    const unsigned hv = *(const unsigned*)&HX[(long long)nb * 128 + c0]; \
                    num0 += w_g * bf2f_lo(hv);                                 \
                    num1 += w_g * bf2f_hi(hv);                                 \
                }                                                              \
            }                                                                  \
            acc0 += num0;                                                      \
            acc1 += num1;                                                      \
        }                                                                      \
    }

    DIR_BLOCK(offs_in, adj_in, h_in, w_in)
    DIR_BLOCK(offs_out, adj_out, h_out, w_out)
#undef DIR_BLOCK

    *(float2*)&out[(long long)n * 128 + c0] = float2{acc0, acc1};
}

extern "C" void kernel_launch(void* const* d_in, const int* in_sizes, int n_in,
                              void* d_out, int out_size, void* d_ws, size_t ws_size,
                              hipStream_t stream) {
    const float* x      = (const float*)d_in[0];
    const int*   ei     = (const int*)  d_in[1];
    const float* W_in   = (const float*)d_in[2];
    const float* as_in  = (const float*)d_in[3];
    const float* ad_in  = (const float*)d_in[4];
    const float* b_in   = (const float*)d_in[5];
    const float* W_out  = (const float*)d_in[6];
    const float* as_out = (const float*)d_in[7];
    const float* ad_out = (const float*)d_in[8];
    const float* b_out  = (const float*)d_in[9];
    float* out = (float*)d_out;

    char* ws = (char*)d_ws;
    const long long NH = (long long)N_NODES * 128;
    unsigned short* x_bf  = (unsigned short*)ws;    ws += NH * 2;
    unsigned short* h_in  = (unsigned short*)ws;    ws += NH * 2;
    unsigned short* h_out = (unsigned short*)ws;    ws += NH * 2;
    unsigned short* Wf    = (unsigned short*)ws;    ws += 2LL * 4 * 9 * 64 * 8 * 2;
    float* asrc_in   = (float*)ws;                  ws += N_NODES * 8 * 4;
    float* adst_in   = (float*)ws;                  ws += N_NODES * 8 * 4;
    float* asrc_out  = (float*)ws;                  ws += N_NODES * 8 * 4;
    float* adst_out  = (float*)ws;                  ws += N_NODES * 8 * 4;
    f16* w_arr_in    = (f16*)ws;                    ws += ((long long)N_EDGES * 8 + 64) * 2;
    f16* w_arr_out   = (f16*)ws;                    ws += ((long long)N_EDGES * 8 + 64) * 2;
    int* binned0     = (int*)ws;                    ws += (long long)N_EDGES * 4;
    int* binned1     = (int*)ws;                    ws += (long long)N_EDGES * 4;
    int* adj_in      = (int*)ws;                    ws += (N_EDGES + 8) * 4;
    int* adj_out     = (int*)ws;                    ws += (N_EDGES + 8) * 4;
    int* offs_in     = (int*)ws;                    ws += (N_NODES + 1) * 4;
    int* offs_out    = (int*)ws;                    ws += (N_NODES + 1) * 4;
    int* bcnt        = (int*)ws;                    ws += 2 * N_PBKT * 4;
    int* boffs0      = (int*)ws;                    ws += (N_PBKT + 1) * 4;
    int* boffs1      = (int*)ws;                    ws += (N_PBKT + 1) * 4;
    int* gcur        = (int*)ws;                    ws += 2 * N_PBKT * 4;

    prep_w_kernel<<<(2 * 4 * 9 * 64 + 255) / 256, 256, 0, stream>>>(
        W_in, W_out, as_in, ad_in, as_out, ad_out, Wf, bcnt,
        adj_in, adj_out, w_arr_in, w_arr_out);
    prep_hist_kernel<<<PREP_BLOCKS + HIST_BLOCKS, 256, 0, stream>>>(
        x, x_bf, ei, bcnt);

    dim3 gemm_grid((N_NODES + 127) / 128, 2);
    gemm_kernel<<<gemm_grid, 256, 0, stream>>>(
        x_bf, Wf, h_in, h_out, asrc_in, adst_in, asrc_out, adst_out);

    bucket_scan_kernel<<<2, 512, 0, stream>>>(
        bcnt, boffs0, boffs1, gcur, offs_in, offs_out);
    partition_kernel<<<dim3((N_EDGES + TILE_E - 1) / TILE_E, 2), 256, 0, stream>>>(
        ei, gcur, binned0, binned1);
    place_kernel<<<dim3(N_PBKT, 2), 256, 0, stream>>>(
        binned0, binned1, boffs0, boffs1, adj_in, adj_out, offs_in, offs_out,
        asrc_in, adst_in, asrc_out, adst_out, w_arr_in, w_arr_out);

    gather_kernel<<<(N_NODES * 64 + 255) / 256, 256, 0, stream>>>(
        offs_in, adj_in, offs_out, adj_out, h_in, h_out,
        w_arr_in, w_arr_out, b_in, b_out, out);
}

// Round 3
// 294.452 us; speedup vs baseline: 1.2476x; 1.2476x over previous
//
#include <hip/hip_runtime.h>

#define N_NODES 100000
#define N_EDGES 800000
#define NEG 0.2f
#define PB_SHIFT 8
#define PB_NODES 256
#define N_PBKT ((N_NODES + PB_NODES - 1) / PB_NODES)   // 391
#define TILE_E 4096
#define EPT 16          // edges per thread in partition (TILE_E / 256)
#define PREP_BLOCKS ((N_NODES * 128 / 4 + 255) / 256)  // 12500
#define HIST_BLOCKS 192

typedef __attribute__((ext_vector_type(8))) short bf16x8;
typedef __attribute__((ext_vector_type(4))) float f32x4;

__device__ inline unsigned short f2bf(float f) {   // RNE f32 -> bf16
    unsigned u = __float_as_uint(f);
    u += 0x7fffu + ((u >> 16) & 1u);
    return (unsigned short)(u >> 16);
}
__device__ inline float bf2f_lo(unsigned u) { return __uint_as_float(u << 16); }
__device__ inline float bf2f_hi(unsigned u) { return __uint_as_float(u & 0xffff0000u); }

// ---------------------------------------------------------------------------
// prep_w: pack W (and Aalpha = W·a, ct==8) into MFMA B-fragment order.
// Also zeroes the bucket-count array and the adj end-pads.
// ---------------------------------------------------------------------------
__global__ __launch_bounds__(256) void prep_w_kernel(
    const float* __restrict__ W_in, const float* __restrict__ W_out,
    const float* __restrict__ as_in, const float* __restrict__ ad_in,
    const float* __restrict__ as_out, const float* __restrict__ ad_out,
    unsigned short* __restrict__ Wf, int* __restrict__ bcnt,
    int* __restrict__ adj_in, int* __restrict__ adj_out)
{
    const int t = blockIdx.x * 256 + threadIdx.x;
    if (t < 2 * N_PBKT) bcnt[t] = 0;
    if (t < 8) { adj_in[N_EDGES + t] = 0; adj_out[N_EDGES + t] = 0; }
    if (t >= 2 * 4 * 9 * 64) return;
    const int lane = t & 63;
    const int rest = t >> 6;
    const int ct  = rest % 9;
    const int kb  = (rest / 9) & 3;
    const int dir = rest / 36;
    const float* W  = dir ? W_out  : W_in;
    const float* as = dir ? as_out : as_in;
    const float* ad = dir ? ad_out : ad_in;
    const int m16 = lane & 15, quad = lane >> 4;

    bf16x8 o;
#pragma unroll
    for (int j = 0; j < 8; ++j) {
        const int k = kb * 32 + quad * 8 + j;
        float v;
        if (ct < 8) {
            v = W[k * 128 + ct * 16 + m16];
        } else {
            const float* av = (m16 < 8) ? as : ad;
            const int hh = m16 & 7;
            v = 0.f;
            for (int c = 0; c < 16; ++c)
                v += W[k * 128 + hh * 16 + c] * av[hh * 16 + c];
        }
        o[j] = (short)f2bf(v);
    }
    *(bf16x8*)&Wf[(long long)t * 8] = o;
}

// ---------------------------------------------------------------------------
// fused prep_x + coarse bucket histogram.
// ---------------------------------------------------------------------------
__global__ __launch_bounds__(256) void prep_hist_kernel(
    const float* __restrict__ x, unsigned short* __restrict__ x_bf,
    const int* __restrict__ ei, int* __restrict__ bcnt)
{
    const int tid = threadIdx.x;
    if (blockIdx.x < PREP_BLOCKS) {
        const int i = (blockIdx.x * 256 + tid) * 4;
        if (i >= N_NODES * 128) return;
        const float4 v = *(const float4*)&x[i];
        ushort4 o;
        o.x = f2bf(v.x); o.y = f2bf(v.y); o.z = f2bf(v.z); o.w = f2bf(v.w);
        *(ushort4*)&x_bf[i] = o;
        return;
    }
    // histogram part
    __shared__ int bh[2 * N_PBKT];
    for (int i = tid; i < 2 * N_PBKT; i += 256) bh[i] = 0;
    __syncthreads();
    const int hb = blockIdx.x - PREP_BLOCKS;
    for (int e = hb * 256 + tid; e < N_EDGES; e += HIST_BLOCKS * 256) {
        const int s = ei[e];
        const int t = ei[N_EDGES + e];
        atomicAdd(&bh[t >> PB_SHIFT], 1);               // dir0: group by dst
        atomicAdd(&bh[N_PBKT + (s >> PB_SHIFT)], 1);    // dir1: group by src
    }
    __syncthreads();
    for (int i = tid; i < 2 * N_PBKT; i += 256) {
        const int v = bh[i];
        if (v) atomicAdd(&bcnt[i], v);
    }
}

// ---------------------------------------------------------------------------
// gemm: h = bf16(x) @ bf16(W) via MFMA; alpha logits from the 9th column tile.
// ---------------------------------------------------------------------------
__global__ __launch_bounds__(256) void gemm_kernel(
    const unsigned short* __restrict__ x_bf,
    const unsigned short* __restrict__ Wf,
    unsigned short* __restrict__ h_in, unsigned short* __restrict__ h_out,
    float* __restrict__ asrc_in, float* __restrict__ adst_in,
    float* __restrict__ asrc_out, float* __restrict__ adst_out)
{
    const int dir = blockIdx.y;
    unsigned short* h = dir ? h_out : h_in;
    float* asrc = dir ? asrc_out : asrc_in;
    float* adst = dir ? adst_out : adst_in;

    const int tid  = threadIdx.x;
    const int lane = tid & 63;
    const int wave = tid >> 6;
    const int m16  = lane & 15;
    const int quad = lane >> 4;
    const int rbase = blockIdx.x * 128 + wave * 32;

    f32x4 acc[2][8];
    f32x4 acc_a[2];
#pragma unroll
    for (int rt = 0; rt < 2; ++rt) {
        acc_a[rt] = f32x4{0.f, 0.f, 0.f, 0.f};
#pragma unroll
        for (int ct = 0; ct < 8; ++ct)
            acc[rt][ct] = f32x4{0.f, 0.f, 0.f, 0.f};
    }

    const unsigned short* wf = Wf + (long long)dir * 4 * 9 * 64 * 8;

#pragma unroll
    for (int kb = 0; kb < 4; ++kb) {
        const int k0 = kb * 32 + quad * 8;
        bf16x8 a[2];
#pragma unroll
        for (int rt = 0; rt < 2; ++rt) {
            int r = rbase + rt * 16 + m16;
            r = r < N_NODES ? r : N_NODES - 1;   // clamp: stores are guarded
            a[rt] = *(const bf16x8*)&x_bf[(long long)r * 128 + k0];
        }
#pragma unroll
        for (int ct = 0; ct < 9; ++ct) {
            const bf16x8 b = *(const bf16x8*)&wf[(long long)((kb * 9 + ct) * 64 + lane) * 8];
            if (ct < 8) {
                acc[0][ct] = __builtin_amdgcn_mfma_f32_16x16x32_bf16(a[0], b, acc[0][ct], 0, 0, 0);
                acc[1][ct] = __builtin_amdgcn_mfma_f32_16x16x32_bf16(a[1], b, acc[1][ct], 0, 0, 0);
            } else {
                acc_a[0] = __builtin_amdgcn_mfma_f32_16x16x32_bf16(a[0], b, acc_a[0], 0, 0, 0);
                acc_a[1] = __builtin_amdgcn_mfma_f32_16x16x32_bf16(a[1], b, acc_a[1], 0, 0, 0);
            }
        }
    }

#pragma unroll
    for (int rt = 0; rt < 2; ++rt) {
#pragma unroll
        for (int r = 0; r < 4; ++r) {
            const int row = rbase + rt * 16 + quad * 4 + r;
            if (row < N_NODES) {
                unsigned short* hp = &h[(long long)row * 128 + m16];
#pragma unroll
                for (int ct = 0; ct < 8; ++ct)
                    hp[ct * 16] = f2bf(acc[rt][ct][r]);
                const float av = acc_a[rt][r];
                if (m16 < 8) asrc[row * 8 + m16] = av;
                else         adst[row * 8 + (m16 - 8)] = av;
            }
        }
    }
}

// ---------------------------------------------------------------------------
// CSR build: scan bucket counts -> boffs (persistent) + gcur (consumed)
// ---------------------------------------------------------------------------
__global__ __launch_bounds__(512) void bucket_scan_kernel(
    const int* __restrict__ bcnt,
    int* __restrict__ boffs0, int* __restrict__ boffs1,
    int* __restrict__ gcur,
    int* __restrict__ offs_in, int* __restrict__ offs_out)
{
    const int dir = blockIdx.x;
    const int* c = bcnt + dir * N_PBKT;
    int* bo = dir ? boffs1 : boffs0;
    int* gc = gcur + dir * N_PBKT;

    __shared__ int sm[512];
    const int tid = threadIdx.x;
    const int v = (tid < N_PBKT) ? c[tid] : 0;
    sm[tid] = v;
    __syncthreads();
#pragma unroll
    for (int off = 1; off < 512; off <<= 1) {
        int t = (tid >= off) ? sm[tid - off] : 0;
        __syncthreads();
        sm[tid] += t;
        __syncthreads();
    }
    if (tid < N_PBKT) {
        const int excl = sm[tid] - v;
        bo[tid] = excl;
        gc[tid] = excl;
    }
    if (tid == N_PBKT - 1) bo[N_PBKT] = sm[tid];   // == N_EDGES
    if (tid == 0) (dir ? offs_out : offs_in)[N_NODES] = N_EDGES;
}

// partition (merged dirs): tile of 4096 edges in registers; both direction
// histograms + scatters from ONE read of ei (round-2's version read ei twice
// and ran 2x the blocks). Pair packed (val<<8)|keylow.
__global__ __launch_bounds__(256) void partition_kernel(
    const int* __restrict__ ei, int* __restrict__ gcur,
    int* __restrict__ binned0, int* __restrict__ binned1)
{
    __shared__ int hist0[N_PBKT];
    __shared__ int curs0[N_PBKT];
    __shared__ int hist1[N_PBKT];
    __shared__ int curs1[N_PBKT];
    const int tid = threadIdx.x;
    for (int i = tid; i < N_PBKT; i += 256) { hist0[i] = 0; hist1[i] = 0; }
    __syncthreads();

    const int e0 = blockIdx.x * TILE_E;
    int sv[EPT], tv[EPT];
#pragma unroll
    for (int i = 0; i < EPT; ++i) {
        const int e = e0 + i * 256 + tid;
        if (e < N_EDGES) {
            sv[i] = ei[e];
            tv[i] = ei[N_EDGES + e];
            atomicAdd(&hist0[tv[i] >> PB_SHIFT], 1);   // dir0: group by dst
            atomicAdd(&hist1[sv[i] >> PB_SHIFT], 1);   // dir1: group by src
        } else {
            sv[i] = -1; tv[i] = 0;
        }
    }
    __syncthreads();
    for (int b = tid; b < N_PBKT; b += 256) {
        int c = hist0[b];
        curs0[b] = c ? atomicAdd(&gcur[b], c) : 0;
        c = hist1[b];
        curs1[b] = c ? atomicAdd(&gcur[N_PBKT + b], c) : 0;
    }
    __syncthreads();
#pragma unroll
    for (int i = 0; i < EPT; ++i) {
        if (sv[i] >= 0) {
            int pos = atomicAdd(&curs0[tv[i] >> PB_SHIFT], 1);
            binned0[pos] = (sv[i] << 8) | (tv[i] & (PB_NODES - 1));
            pos = atomicAdd(&curs1[sv[i] >> PB_SHIFT], 1);
            binned1[pos] = (tv[i] << 8) | (sv[i] & (PB_NODES - 1));
        }
    }
}

// place (round-0 form): one block per bucket; fine count+scan+cursors in LDS;
// adj writes land in a contiguous ~8KB region. Pure scatter — no w pipeline
// (rounds 1/2 proved producer-side w computation is latency-bound and costs
// more than it saves in gather).
__global__ __launch_bounds__(256) void place_kernel(
    const int* __restrict__ binned0, const int* __restrict__ binned1,
    const int* __restrict__ boffs0, const int* __restrict__ boffs1,
    int* __restrict__ adj_in, int* __restrict__ adj_out,
    int* __restrict__ offs_in, int* __restrict__ offs_out)
{
    const int b   = blockIdx.x;
    const int dir = blockIdx.y;
    const int* bp = dir ? binned1 : binned0;
    const int* bo = dir ? boffs1  : boffs0;
    int* adj  = dir ? adj_out  : adj_in;
    int* offs = dir ? offs_out : offs_in;

    const int base = b << PB_SHIFT;
    const int beg = bo[b], end = bo[b + 1];
    const int tid = threadIdx.x;

    __shared__ int cnt[PB_NODES];
    __shared__ int sc[PB_NODES];
    __shared__ int cur[PB_NODES];

    cnt[tid] = 0;
    __syncthreads();
    for (int p = beg + tid; p < end; p += 256)
        atomicAdd(&cnt[bp[p] & (PB_NODES - 1)], 1);
    __syncthreads();
    const int v = cnt[tid];
    sc[tid] = v;
    __syncthreads();
#pragma unroll
    for (int off = 1; off < PB_NODES; off <<= 1) {
        int t = (tid >= off) ? sc[tid - off] : 0;
        __syncthreads();
        sc[tid] += t;
        __syncthreads();
    }
    const int excl = beg + sc[tid] - v;
    cur[tid] = excl;
    const int node = base + tid;
    if (node < N_NODES) offs[node] = excl;
    __syncthreads();
    for (int p = beg + tid; p < end; p += 256) {
        const int pk = bp[p];
        adj[atomicAdd(&cur[pk & (PB_NODES - 1)], 1)] = pk >> 8;
    }
}

// ---------------------------------------------------------------------------
// Gather v5: one wave per node, wave-uniform n (readfirstlane) so offs/adj go
// through the scalar pipe. Keeps round-1's structural wins (single padded
// branch-free loop, scalar adj for h-row addresses, one shfl per visit) but
// computes w inline (per-lane asrc load + leaky + exp — 1 exp per 8 visits)
// so no producer-side w pipeline is needed. den via 3x shfl_xor at the end.
// ---------------------------------------------------------------------------
__global__ __launch_bounds__(256) void gather_kernel(
    const int* __restrict__ offs_in, const int* __restrict__ adj_in,
    const int* __restrict__ offs_out, const int* __restrict__ adj_out,
    const unsigned short* __restrict__ h_in, const unsigned short* __restrict__ h_out,
    const float* __restrict__ asrc_in, const float* __restrict__ adst_in,
    const float* __restrict__ asrc_out, const float* __restrict__ adst_out,
    const float* __restrict__ b_in, const float* __restrict__ b_out,
    float* __restrict__ out)
{
    int n = (blockIdx.x * 256 + threadIdx.x) >> 6;
    if (n >= N_NODES) return;
    n = __builtin_amdgcn_readfirstlane(n);
    const int lane = threadIdx.x & 63;
    const int c0 = lane * 2;
    const int hh = lane >> 3;        // head this lane accumulates for
    const int g8 = lane & 7;         // neighbor slot this lane owns
    const int grpbase = lane & 56;   // hh*8: base lane of this head group

    float acc0 = b_in[c0] + b_out[c0];
    float acc1 = b_in[c0 + 1] + b_out[c0 + 1];

#define DIR_BLOCK(OFFS, ADJ, HX, ASRC, ADST)                                   \
    {                                                                          \
        const int beg = OFFS[n], end = OFFS[n + 1];                            \
        if (end > beg) {                                                       \
            const float ad = ADST[n * 8 + hh];                                 \
            float num0 = 0.f, num1 = 0.f, den = 0.f;                           \
            for (int p = beg; p < end; p += 8) {                               \
                const int q = p + g8;                                          \
                const int nbv = ADJ[q];               /* vector ld, padded */  \
                float l = ASRC[nbv * 8 + hh] + ad;                             \
                l = l > 0.f ? l : NEG * l;                                     \
                float w = __expf(l);                                           \
                w = (q < end) ? w : 0.f;                                       \
                den += w;                                                      \
                _Pragma("unroll")                                              \
                for (int g = 0; g < 8; ++g) {                                  \
                    const int nb = ADJ[p + g];        /* scalar (uniform) */   \
                    const float w_g = __shfl(w, grpbase + g, 64);              \
                    const unsigned hv = *(const unsigned*)&HX[(long long)nb * 128 + c0]; \
                    num0 += w_g * bf2f_lo(hv);                                 \
                    num1 += w_g * bf2f_hi(hv);                                 \
                }                                                              \
            }                                                                  \
            den += __shfl_xor(den, 1, 64);                                     \
            den += __shfl_xor(den, 2, 64);                                     \
            den += __shfl_xor(den, 4, 64);                                     \
            const float rden = 1.f / den;                                      \
            acc0 += num0 * rden;                                               \
            acc1 += num1 * rden;                                               \
        }                                                                      \
    }

    DIR_BLOCK(offs_in, adj_in, h_in, asrc_in, adst_in)
    DIR_BLOCK(offs_out, adj_out, h_out, asrc_out, adst_out)
#undef DIR_BLOCK

    *(float2*)&out[(long long)n * 128 + c0] = float2{acc0, acc1};
}

extern "C" void kernel_launch(void* const* d_in, const int* in_sizes, int n_in,
                              void* d_out, int out_size, void* d_ws, size_t ws_size,
                              hipStream_t stream) {
    const float* x      = (const float*)d_in[0];
    const int*   ei     = (const int*)  d_in[1];
    const float* W_in   = (const float*)d_in[2];
    const float* as_in  = (const float*)d_in[3];
    const float* ad_in  = (const float*)d_in[4];
    const float* b_in   = (const float*)d_in[5];
    const float* W_out  = (const float*)d_in[6];
    const float* as_out = (const float*)d_in[7];
    const float* ad_out = (const float*)d_in[8];
    const float* b_out  = (const float*)d_in[9];
    float* out = (float*)d_out;

    char* ws = (char*)d_ws;
    const long long NH = (long long)N_NODES * 128;
    unsigned short* x_bf  = (unsigned short*)ws;    ws += NH * 2;
    unsigned short* h_in  = (unsigned short*)ws;    ws += NH * 2;
    unsigned short* h_out = (unsigned short*)ws;    ws += NH * 2;
    unsigned short* Wf    = (unsigned short*)ws;    ws += 2LL * 4 * 9 * 64 * 8 * 2;
    float* asrc_in   = (float*)ws;                  ws += N_NODES * 8 * 4;
    float* adst_in   = (float*)ws;                  ws += N_NODES * 8 * 4;
    float* asrc_out  = (float*)ws;                  ws += N_NODES * 8 * 4;
    float* adst_out  = (float*)ws;                  ws += N_NODES * 8 * 4;
    int* binned0     = (int*)ws;                    ws += (long long)N_EDGES * 4;
    int* binned1     = (int*)ws;                    ws += (long long)N_EDGES * 4;
    int* adj_in      = (int*)ws;                    ws += (N_EDGES + 8) * 4;
    int* adj_out     = (int*)ws;                    ws += (N_EDGES + 8) * 4;
    int* offs_in     = (int*)ws;                    ws += (N_NODES + 1) * 4;
    int* offs_out    = (int*)ws;                    ws += (N_NODES + 1) * 4;
    int* bcnt        = (int*)ws;                    ws += 2 * N_PBKT * 4;
    int* boffs0      = (int*)ws;                    ws += (N_PBKT + 1) * 4;
    int* boffs1      = (int*)ws;                    ws += (N_PBKT + 1) * 4;
    int* gcur        = (int*)ws;                    ws += 2 * N_PBKT * 4;

    prep_w_kernel<<<(2 * 4 * 9 * 64 + 255) / 256, 256, 0, stream>>>(
        W_in, W_out, as_in, ad_in, as_out, ad_out, Wf, bcnt, adj_in, adj_out);
    prep_hist_kernel<<<PREP_BLOCKS + HIST_BLOCKS, 256, 0, stream>>>(
        x, x_bf, ei, bcnt);

    dim3 gemm_grid((N_NODES + 127) / 128, 2);
    gemm_kernel<<<gemm_grid, 256, 0, stream>>>(
        x_bf, Wf, h_in, h_out, asrc_in, adst_in, asrc_out, adst_out);

    bucket_scan_kernel<<<2, 512, 0, stream>>>(
        bcnt, boffs0, boffs1, gcur, offs_in, offs_out);
    partition_kernel<<<(N_EDGES + TILE_E - 1) / TILE_E, 256, 0, stream>>>(
        ei, gcur, binned0, binned1);
    place_kernel<<<dim3(N_PBKT, 2), 256, 0, stream>>>(
        binned0, binned1, boffs0, boffs1, adj_in, adj_out, offs_in, offs_out);

    gather_kernel<<<(N_NODES * 64 + 255) / 256, 256, 0, stream>>>(
        offs_in, adj_in, offs_out, adj_out, h_in, h_out,
        asrc_in, adst_in, asrc_out, adst_out, b_in, b_out, out);
}